// Round 3
// baseline (350.731 us; speedup 1.0000x reference)
//
#include <hip/hip_runtime.h>
#include <hip/hip_bf16.h>
#include <cstdint>

typedef unsigned short ushort_t;
typedef unsigned int uint_t;
typedef __bf16 bf16x8 __attribute__((ext_vector_type(8)));
typedef float f32x4 __attribute__((ext_vector_type(4)));

#define B_SZ 32
#define C_IN 256
#define C_OUT 256
#define H_SZ 56
#define W_SZ 56
#define HW 3136          // 56*56
#define HP 58            // padded H (halo 1 each side)
#define WP 58            // padded W
#define PPAD 3364        // 58*58 padded cells per image
#define BN_EPS 1e-5f
#define K_ZERO 128       // channels zeroed per batch; 128 survive

__device__ __forceinline__ ushort_t f2bf(float f) {
    unsigned int u = __builtin_bit_cast(unsigned int, f);
    unsigned int r = (u + 0x7fffu + ((u >> 16) & 1u)) >> 16;
    return (ushort_t)r;
}

__device__ __forceinline__ void load_lds16(const void* gptr, void* ldsptr) {
    __builtin_amdgcn_global_load_lds(
        (const __attribute__((address_space(1))) unsigned int*)(uintptr_t)gptr,
        (__attribute__((address_space(3))) unsigned int*)(uintptr_t)ldsptr,
        16, 0, 0);
}

// ---------------------------------------------------------------------------
// Kernel 1: weights OIHW fp32 -> Wt[tap][co][ci] bf16; BN consts; zero s.
// ---------------------------------------------------------------------------
__global__ __launch_bounds__(256) void prep_w_kernel(const float* __restrict__ w,
                                                     const float* __restrict__ gamma,
                                                     const float* __restrict__ beta,
                                                     const float* __restrict__ mean,
                                                     const float* __restrict__ var,
                                                     ushort_t* __restrict__ Wt,
                                                     float* __restrict__ bninv,
                                                     float* __restrict__ bnadd,
                                                     float* __restrict__ s) {
    int idx = blockIdx.x * 256 + threadIdx.x;
    if (idx < 9 * C_OUT * C_IN) {
        int tap = idx >> 16;
        int rem = idx & 65535;
        int co = rem >> 8, ci = rem & 255;
        Wt[idx] = f2bf(w[(size_t)(co * C_IN + ci) * 9 + tap]);
    }
    if (blockIdx.x < 32) s[idx] = 0.f;
    if (blockIdx.x == 32 && threadIdx.x < C_OUT) {
        int c = threadIdx.x;
        float inv = gamma[c] * rsqrtf(var[c] + BN_EPS);
        bninv[c] = inv;
        bnadd[c] = beta[c] - mean[c] * inv;
    }
}

// ---------------------------------------------------------------------------
// Kernel 2: x NCHW fp32 -> padded NHWC bf16, fused abs-mean partials + halo.
// grid: (4 ci-tiles, 56 h, 32 b), block 256
// ---------------------------------------------------------------------------
__global__ __launch_bounds__(256) void prep_x_kernel(const float* __restrict__ x,
                                                     ushort_t* __restrict__ xbp,
                                                     float* __restrict__ s) {
    const int cit = blockIdx.x, h = blockIdx.y, b = blockIdx.z;
    __shared__ float tile[64][57];
    __shared__ float red2[256];
    const int t = threadIdx.x;
    const float* src = x + ((size_t)(b * C_IN + cit * 64) * H_SZ + h) * W_SZ;
    for (int i = t; i < 64 * 14; i += 256) {
        int ci = i / 14, w4 = (i - ci * 14) * 4;
        float4 v = *(const float4*)(src + (size_t)ci * HW + w4);
        tile[ci][w4] = v.x; tile[ci][w4 + 1] = v.y;
        tile[ci][w4 + 2] = v.z; tile[ci][w4 + 3] = v.w;
    }
    __syncthreads();
    {
        int ci = t & 63, wg = t >> 6;
        float a = 0.f;
#pragma unroll
        for (int j = 0; j < 14; j++) a += fabsf(tile[ci][wg * 14 + j]);
        red2[t] = a;
    }
    __syncthreads();
    if (t < 64) {
        float tot = red2[t] + red2[t + 64] + red2[t + 128] + red2[t + 192];
        atomicAdd(&s[b * C_IN + cit * 64 + t], tot * (1.0f / (float)HW));
    }
    const uint2 z2 = make_uint2(0u, 0u);
    for (int i = t; i < W_SZ * 16; i += 256) {
        int w = i >> 4, c4 = (i & 15) * 4;
        uint_t lo = (uint_t)f2bf(tile[c4][w])     | ((uint_t)f2bf(tile[c4 + 1][w]) << 16);
        uint_t hi = (uint_t)f2bf(tile[c4 + 2][w]) | ((uint_t)f2bf(tile[c4 + 3][w]) << 16);
        size_t dst = ((size_t)((b * HP + h + 1) * WP + (w + 1))) * C_IN + cit * 64 + c4;
        *(uint2*)&xbp[dst] = make_uint2(lo, hi);
    }
    if (t < 32) {
        int side = t >> 4, c4 = (t & 15) * 4;
        size_t dst = ((size_t)((b * HP + h + 1) * WP + side * 57)) * C_IN + cit * 64 + c4;
        *(uint2*)&xbp[dst] = z2;
    }
    if (h == 0 || h == 55) {
        int prow = (h == 0) ? 0 : 57;
        for (int i = t; i < 58 * 16; i += 256) {
            int w = i >> 4, c4 = (i & 15) * 4;
            size_t dst = ((size_t)((b * HP + prow) * WP + w)) * C_IN + cit * 64 + c4;
            *(uint2*)&xbp[dst] = z2;
        }
    }
}

// ---------------------------------------------------------------------------
// Kernel 3: gate -> per-batch channel permutation + compacted scales.
// ---------------------------------------------------------------------------
__global__ __launch_bounds__(256) void gate_kernel(const float* __restrict__ s,
                                                   const float* __restrict__ gw,
                                                   const float* __restrict__ gb,
                                                   ushort_t* __restrict__ perm,
                                                   float* __restrict__ cscale) {
    const int b = blockIdx.x, t = threadIdx.x;
    __shared__ float sh_s[C_IN], sh_g[C_OUT], red[256];
    sh_s[t] = s[b * C_IN + t];
    __syncthreads();
    float acc = gb[t];
    const float* wr = gw + (size_t)t * C_IN;
    for (int ci = 0; ci < C_IN; ci++) acc += sh_s[ci] * wr[ci];
    float g = fmaxf(acc, 0.f);
    sh_g[t] = g;
    __syncthreads();
    int cnt = 0;
    for (int j = 0; j < C_OUT; j++) {
        float gj = sh_g[j];
        cnt += (gj < g) || (gj == g && j < t);
    }
    float tv = (cnt >= K_ZERO) ? g : 0.f;
    red[t] = tv;
    __syncthreads();
    for (int off = 128; off > 0; off >>= 1) {
        if (t < off) red[t] += red[t + off];
        __syncthreads();
    }
    if (cnt >= K_ZERO) {
        int pos = cnt - K_ZERO;
        perm[b * C_OUT + pos] = (ushort_t)t;
        cscale[b * K_ZERO + pos] = tv * ((float)C_OUT / red[0]);
    } else {
        perm[b * C_OUT + K_ZERO + cnt] = (ushort_t)t;
    }
}

// ---------------------------------------------------------------------------
// Kernel 4: implicit-GEMM conv, A-window tap-reuse edition.
// Diagnosis r2: L2-request-rate/stage-latency bound (MfmaUtil 25%, HBM 19%,
// FETCH 35MB all-L2-hit): A was re-staged 9x (once per tap) = 576 KB/block
// for a ~150 KB unique window -> 14.7M L2 line-requests chip-wide.
// Fix: in PADDED flat coords pp=(h+1)*58+(w+1), tap (dy,dx)'s row is just
// pp + dy*58 + dx. Stage ONE contiguous 256-row pp-window (32 KB) per
// ci-quarter; all 9 taps read it at dynamic LDS row wr = wrb + dy*58+dx
// with the same row-keyed XOR swizzle. A staging 576->128 KB/block; total
// L2->LDS 1152->704 KB/block. B path, sync structure, MFMA loop unchanged.
// Window proof: valid p -> wr in [0,250) subset [0,256); clamp at 3363 only
// touches tile-24 rows that valid outputs never read (max wr read = 183,
// clamp starts at w_idx 184). pp0>=59 so lower bound never clamps.
// Swizzle: tile-major within XCD -> co-resident CU blocks are SAME batch,
// tiles {t,t+8,t+16}: identical B lines per stage (L1/MSHR coalescing bet).
// ---------------------------------------------------------------------------
__global__ __launch_bounds__(256, 3) void conv_kernel(const ushort_t* __restrict__ xbp,
                                                      const ushort_t* __restrict__ Wt,
                                                      const float* __restrict__ bninv,
                                                      const float* __restrict__ bnadd,
                                                      const ushort_t* __restrict__ perm,
                                                      const float* __restrict__ cscale,
                                                      float* __restrict__ out) {
    __shared__ __align__(16) ushort_t Aw[256 * 64];  // 32 KB pp-window (256 rows x 64 ci)
    __shared__ __align__(16) ushort_t Bs[128 * 64];  // 16 KB
    const int t = threadIdx.x;
    // XCD-chunked (800%8==0 bijective), tile-major within XCD:
    // XCD x hosts batches 4x..4x+3; idx cycles batch fastest -> CU strides of
    // 32 land on the SAME batch, tiles 8 apart.
    const int bxr = blockIdx.x;
    const int idx = bxr >> 3;
    const int b = (bxr & 7) * 4 + (idx & 3);
    const int tile = idx >> 2;               // 0..24
    const int lane = t & 63;
    const int wv = t >> 6;
    const int waveM = wv >> 1, waveN = wv & 1;

    const int p0 = tile * 128;
    const int h0 = p0 / W_SZ, w0 = p0 - h0 * W_SZ;
    const int pp0 = (h0 + 1) * WP + (w0 + 1);

    // staging: chunk q = i*256+t -> LDS row i*32+(t>>3), stored col t&7,
    // global col (t&7)^(row&7)   (row = window row / B row)
    const int srow = t >> 3;
    const int gxor8 = ((t & 7) ^ (srow & 7)) * 8;
    int awin[8], wrowB[4];
#pragma unroll
    for (int i = 0; i < 8; i++) {
        int wrow_g = pp0 - 59 + i * 32 + srow;           // >= 0 always
        wrow_g = wrow_g > (PPAD - 1) ? (PPAD - 1) : wrow_g;  // tile-24 tail clamp
        awin[i] = (b * PPAD + wrow_g) * C_IN + gxor8;
    }
#pragma unroll
    for (int i = 0; i < 4; i++) {
        int co = perm[b * C_OUT + i * 32 + srow];  // surviving channel gather
        wrowB[i] = co * C_IN + gxor8;
    }
    ushort_t* ldsA = Aw + t * 8;
    ushort_t* ldsB = Bs + t * 8;

    // B fragment LDS byte offsets (static, as before)
    int boff[2][4];
#pragma unroll
    for (int ks = 0; ks < 2; ks++) {
        int c = (lane >> 4) + ks * 4;
#pragma unroll
        for (int nt = 0; nt < 4; nt++) {
            int rb = waveN * 64 + nt * 16 + (lane & 15);
            boff[ks][nt] = (rb * 8 + (c ^ (rb & 7))) * 16;
        }
    }

    // A fragment window row base per mt (per-lane; taps add dy*58+dx)
    int wrb[4];
#pragma unroll
    for (int mt = 0; mt < 4; mt++) {
        int pl = p0 + waveM * 64 + mt * 16 + (lane & 15);
        pl = pl < HW ? pl : HW - 1;          // tail rows: read valid window, store masked
        int hh = pl / W_SZ, ww = pl - hh * W_SZ;
        wrb[mt] = (hh + 1) * WP + (ww + 1) - pp0 + 59;
    }

    f32x4 acc[4][4];
#pragma unroll
    for (int i = 0; i < 4; i++)
#pragma unroll
        for (int j = 0; j < 4; j++) acc[i][j] = (f32x4){0.f, 0.f, 0.f, 0.f};

    const char* Abc = (const char*)Aw;
    const char* Bbc = (const char*)Bs;

    for (int cq = 0; cq < 4; cq++) {
        const int ci0 = cq * 64;
        // stage the A pp-window ONCE per ci-quarter (8 x 4 KB)
#pragma unroll
        for (int i = 0; i < 8; i++)
            load_lds16(xbp + awin[i] + ci0, ldsA + i * 2048);
        for (int tap = 0; tap < 9; tap++) {
            const int dtap = (tap / 3 - 1) * WP + (tap % 3 - 1);
            const int woff = tap * (C_OUT * C_IN);
#pragma unroll
            for (int i = 0; i < 4; i++)
                load_lds16(Wt + wrowB[i] + woff + ci0, ldsB + i * 2048);
            __syncthreads();
#pragma unroll
            for (int ks = 0; ks < 2; ks++) {
                bf16x8 af[4], bf[4];
                const int c = (lane >> 4) + ks * 4;
#pragma unroll
                for (int mt = 0; mt < 4; mt++) {
                    int wr = wrb[mt] + dtap;
                    af[mt] = *(const bf16x8*)(Abc + wr * 128 + ((c ^ (wr & 7)) << 4));
                }
#pragma unroll
                for (int nt = 0; nt < 4; nt++) bf[nt] = *(const bf16x8*)(Bbc + boff[ks][nt]);
#pragma unroll
                for (int mt = 0; mt < 4; mt++)
#pragma unroll
                    for (int nt = 0; nt < 4; nt++)
                        acc[mt][nt] = __builtin_amdgcn_mfma_f32_16x16x32_bf16(
                            af[mt], bf[nt], acc[mt][nt], 0, 0, 0);
            }
            __syncthreads();
        }
    }

    // epilogue: y = relu(acc*inv + add) * cscale, scatter to real channel;
    // plus zero-fill the dead channels over the same p rows.
    int coK[4], coD[4];
    float invK[4], addK[4], tscK[4];
#pragma unroll
    for (int nt = 0; nt < 4; nt++) {
        int j = waveN * 64 + nt * 16 + (lane & 15);
        coK[nt] = perm[b * C_OUT + j];
        coD[nt] = perm[b * C_OUT + K_ZERO + j];
        invK[nt] = bninv[coK[nt]];
        addK[nt] = bnadd[coK[nt]];
        tscK[nt] = cscale[b * K_ZERO + j];
    }
    const float4 z4 = make_float4(0.f, 0.f, 0.f, 0.f);
#pragma unroll
    for (int mt = 0; mt < 4; mt++) {
        int pl0 = p0 + waveM * 64 + mt * 16 + (lane >> 4) * 4;
        if (pl0 < HW) {
#pragma unroll
            for (int nt = 0; nt < 4; nt++) {
                float inv = invK[nt], add = addK[nt], tsc = tscK[nt];
                float4 o;
                o.x = fmaxf(acc[mt][nt][0] * inv + add, 0.f) * tsc;
                o.y = fmaxf(acc[mt][nt][1] * inv + add, 0.f) * tsc;
                o.z = fmaxf(acc[mt][nt][2] * inv + add, 0.f) * tsc;
                o.w = fmaxf(acc[mt][nt][3] * inv + add, 0.f) * tsc;
                *(float4*)(out + (size_t)(b * C_OUT + coK[nt]) * HW + pl0) = o;
                *(float4*)(out + (size_t)(b * C_OUT + coD[nt]) * HW + pl0) = z4;
            }
        }
    }
}

// ---------------------------------------------------------------------------
extern "C" void kernel_launch(void* const* d_in, const int* in_sizes, int n_in,
                              void* d_out, int out_size, void* d_ws, size_t ws_size,
                              hipStream_t stream) {
    const float* x      = (const float*)d_in[0];
    const float* conv_w = (const float*)d_in[1];
    const float* gate_w = (const float*)d_in[2];
    const float* gate_b = (const float*)d_in[3];
    const float* bn_g   = (const float*)d_in[4];
    const float* bn_b   = (const float*)d_in[5];
    const float* bn_m   = (const float*)d_in[6];
    const float* bn_v   = (const float*)d_in[7];
    float* out = (float*)d_out;

    char* ws = (char*)d_ws;
    float*    s      = (float*)(ws + 0);          // 8192 f
    ushort_t* perm   = (ushort_t*)(ws + 32768);   // 32*256 u16 (16 KB)
    float*    cscale = (float*)(ws + 49152);      // 32*128 f  (16 KB)
    float*    bninv  = (float*)(ws + 65536);      // 256 f
    float*    bnadd  = (float*)(ws + 66560);      // 256 f
    ushort_t* Wt     = (ushort_t*)(ws + 67584);   // 589824 bf16
    ushort_t* xbp    = (ushort_t*)(ws + 1247232); // 32*58*58*256 bf16

    prep_w_kernel<<<2304, 256, 0, stream>>>(conv_w, bn_g, bn_b, bn_m, bn_v, Wt, bninv, bnadd, s);
    prep_x_kernel<<<dim3(4, 56, 32), 256, 0, stream>>>(x, xbp, s);
    gate_kernel<<<32, 256, 0, stream>>>(s, gate_w, gate_b, perm, cscale);
    conv_kernel<<<dim3(25 * 32), 256, 0, stream>>>(xbp, Wt, bninv, bnadd, perm, cscale, out);
}

// Round 4
// 345.733 us; speedup vs baseline: 1.0145x; 1.0145x over previous
//
#include <hip/hip_runtime.h>
#include <hip/hip_bf16.h>
#include <cstdint>

typedef unsigned short ushort_t;
typedef unsigned int uint_t;
typedef __bf16 bf16x8 __attribute__((ext_vector_type(8)));
typedef float f32x4 __attribute__((ext_vector_type(4)));

#define B_SZ 32
#define C_IN 256
#define C_OUT 256
#define H_SZ 56
#define W_SZ 56
#define HW 3136          // 56*56
#define HP 58            // padded H (halo 1 each side)
#define WP 58            // padded W
#define PPAD 3364        // 58*58 padded cells per image
#define BN_EPS 1e-5f
#define K_ZERO 128       // channels zeroed per batch; 128 survive

__device__ __forceinline__ ushort_t f2bf(float f) {
    unsigned int u = __builtin_bit_cast(unsigned int, f);
    unsigned int r = (u + 0x7fffu + ((u >> 16) & 1u)) >> 16;
    return (ushort_t)r;
}

__device__ __forceinline__ void load_lds16(const void* gptr, void* ldsptr) {
    __builtin_amdgcn_global_load_lds(
        (const __attribute__((address_space(1))) unsigned int*)(uintptr_t)gptr,
        (__attribute__((address_space(3))) unsigned int*)(uintptr_t)ldsptr,
        16, 0, 0);
}

// ---------------------------------------------------------------------------
// Kernel 1: weights OIHW fp32 -> Wt[tap][co][ci] bf16; BN consts; zero s.
// ---------------------------------------------------------------------------
__global__ __launch_bounds__(256) void prep_w_kernel(const float* __restrict__ w,
                                                     const float* __restrict__ gamma,
                                                     const float* __restrict__ beta,
                                                     const float* __restrict__ mean,
                                                     const float* __restrict__ var,
                                                     ushort_t* __restrict__ Wt,
                                                     float* __restrict__ bninv,
                                                     float* __restrict__ bnadd,
                                                     float* __restrict__ s) {
    int idx = blockIdx.x * 256 + threadIdx.x;
    if (idx < 9 * C_OUT * C_IN) {
        int tap = idx >> 16;
        int rem = idx & 65535;
        int co = rem >> 8, ci = rem & 255;
        Wt[idx] = f2bf(w[(size_t)(co * C_IN + ci) * 9 + tap]);
    }
    if (blockIdx.x < 32) s[idx] = 0.f;
    if (blockIdx.x == 32 && threadIdx.x < C_OUT) {
        int c = threadIdx.x;
        float inv = gamma[c] * rsqrtf(var[c] + BN_EPS);
        bninv[c] = inv;
        bnadd[c] = beta[c] - mean[c] * inv;
    }
}

// ---------------------------------------------------------------------------
// Kernel 2: x NCHW fp32 -> padded NHWC bf16, fused abs-mean partials + halo.
// grid: (4 ci-tiles, 56 h, 32 b), block 256
// ---------------------------------------------------------------------------
__global__ __launch_bounds__(256) void prep_x_kernel(const float* __restrict__ x,
                                                     ushort_t* __restrict__ xbp,
                                                     float* __restrict__ s) {
    const int cit = blockIdx.x, h = blockIdx.y, b = blockIdx.z;
    __shared__ float tile[64][57];
    __shared__ float red2[256];
    const int t = threadIdx.x;
    const float* src = x + ((size_t)(b * C_IN + cit * 64) * H_SZ + h) * W_SZ;
    for (int i = t; i < 64 * 14; i += 256) {
        int ci = i / 14, w4 = (i - ci * 14) * 4;
        float4 v = *(const float4*)(src + (size_t)ci * HW + w4);
        tile[ci][w4] = v.x; tile[ci][w4 + 1] = v.y;
        tile[ci][w4 + 2] = v.z; tile[ci][w4 + 3] = v.w;
    }
    __syncthreads();
    {
        int ci = t & 63, wg = t >> 6;
        float a = 0.f;
#pragma unroll
        for (int j = 0; j < 14; j++) a += fabsf(tile[ci][wg * 14 + j]);
        red2[t] = a;
    }
    __syncthreads();
    if (t < 64) {
        float tot = red2[t] + red2[t + 64] + red2[t + 128] + red2[t + 192];
        atomicAdd(&s[b * C_IN + cit * 64 + t], tot * (1.0f / (float)HW));
    }
    const uint2 z2 = make_uint2(0u, 0u);
    for (int i = t; i < W_SZ * 16; i += 256) {
        int w = i >> 4, c4 = (i & 15) * 4;
        uint_t lo = (uint_t)f2bf(tile[c4][w])     | ((uint_t)f2bf(tile[c4 + 1][w]) << 16);
        uint_t hi = (uint_t)f2bf(tile[c4 + 2][w]) | ((uint_t)f2bf(tile[c4 + 3][w]) << 16);
        size_t dst = ((size_t)((b * HP + h + 1) * WP + (w + 1))) * C_IN + cit * 64 + c4;
        *(uint2*)&xbp[dst] = make_uint2(lo, hi);
    }
    if (t < 32) {
        int side = t >> 4, c4 = (t & 15) * 4;
        size_t dst = ((size_t)((b * HP + h + 1) * WP + side * 57)) * C_IN + cit * 64 + c4;
        *(uint2*)&xbp[dst] = z2;
    }
    if (h == 0 || h == 55) {
        int prow = (h == 0) ? 0 : 57;
        for (int i = t; i < 58 * 16; i += 256) {
            int w = i >> 4, c4 = (i & 15) * 4;
            size_t dst = ((size_t)((b * HP + prow) * WP + w)) * C_IN + cit * 64 + c4;
            *(uint2*)&xbp[dst] = z2;
        }
    }
}

// ---------------------------------------------------------------------------
// Kernel 3: gate -> per-batch channel permutation + compacted scales.
// ---------------------------------------------------------------------------
__global__ __launch_bounds__(256) void gate_kernel(const float* __restrict__ s,
                                                   const float* __restrict__ gw,
                                                   const float* __restrict__ gb,
                                                   ushort_t* __restrict__ perm,
                                                   float* __restrict__ cscale) {
    const int b = blockIdx.x, t = threadIdx.x;
    __shared__ float sh_s[C_IN], sh_g[C_OUT], red[256];
    sh_s[t] = s[b * C_IN + t];
    __syncthreads();
    float acc = gb[t];
    const float* wr = gw + (size_t)t * C_IN;
    for (int ci = 0; ci < C_IN; ci++) acc += sh_s[ci] * wr[ci];
    float g = fmaxf(acc, 0.f);
    sh_g[t] = g;
    __syncthreads();
    int cnt = 0;
    for (int j = 0; j < C_OUT; j++) {
        float gj = sh_g[j];
        cnt += (gj < g) || (gj == g && j < t);
    }
    float tv = (cnt >= K_ZERO) ? g : 0.f;
    red[t] = tv;
    __syncthreads();
    for (int off = 128; off > 0; off >>= 1) {
        if (t < off) red[t] += red[t + off];
        __syncthreads();
    }
    if (cnt >= K_ZERO) {
        int pos = cnt - K_ZERO;
        perm[b * C_OUT + pos] = (ushort_t)t;
        cscale[b * K_ZERO + pos] = tv * ((float)C_OUT / red[0]);
    } else {
        perm[b * C_OUT + K_ZERO + cnt] = (ushort_t)t;
    }
}

// ---------------------------------------------------------------------------
// Kernel 4: implicit-GEMM conv, A-window tap-reuse + tile-fastest mapping.
// r3 post-mortem: A-window was sound, but intra-XCD batch-fastest order put
// 4 disjoint batches co-resident (A footprint ~6.7 MB > 4 MB L2) -> thrash
// (FETCH 35->68 MB, WRITE 115->143 MB from partial-line out evictions).
// Fix: restore r2's TILE-FASTEST order (b = 4x + idx/25, tile = idx%25):
// co-resident blocks are same-batch adjacent tiles whose 256-row windows
// overlap 50% and share B/perm lines -> XCD A footprint ~3.4 MB (proven by
// r2's FETCH=35 MB). A-window staging (once per cq, all 9 taps read LDS at
// dynamic row wr = wrb + dy*58+dx, row-keyed XOR swizzle) kept verbatim:
// staged bytes 1152->704 KB/block. Known minor cost: +3-row jumps at W
// boundaries give ~0.5M conflict-cycles (~0.8 us) - accepted.
// ---------------------------------------------------------------------------
__global__ __launch_bounds__(256, 3) void conv_kernel(const ushort_t* __restrict__ xbp,
                                                      const ushort_t* __restrict__ Wt,
                                                      const float* __restrict__ bninv,
                                                      const float* __restrict__ bnadd,
                                                      const ushort_t* __restrict__ perm,
                                                      const float* __restrict__ cscale,
                                                      float* __restrict__ out) {
    __shared__ __align__(16) ushort_t Aw[256 * 64];  // 32 KB pp-window (256 rows x 64 ci)
    __shared__ __align__(16) ushort_t Bs[128 * 64];  // 16 KB
    const int t = threadIdx.x;
    // XCD-chunked (800%8==0 bijective), TILE-FASTEST within XCD (r2-proven):
    // XCD x hosts batches 4x..4x+3; consecutive idx = same batch, adjacent
    // tiles -> co-resident windows overlap 50%, B lines shared.
    const int bxr = blockIdx.x;
    const int idx = bxr >> 3;                // 0..99 within XCD
    const int b = (bxr & 7) * 4 + idx / 25;  // 4 consecutive batches per XCD
    const int tile = idx % 25;               // 0..24, fastest
    const int lane = t & 63;
    const int wv = t >> 6;
    const int waveM = wv >> 1, waveN = wv & 1;

    const int p0 = tile * 128;
    const int h0 = p0 / W_SZ, w0 = p0 - h0 * W_SZ;
    const int pp0 = (h0 + 1) * WP + (w0 + 1);

    // staging: chunk q = i*256+t -> LDS row i*32+(t>>3), stored col t&7,
    // global col (t&7)^(row&7)   (row = window row / B row)
    const int srow = t >> 3;
    const int gxor8 = ((t & 7) ^ (srow & 7)) * 8;
    int awin[8], wrowB[4];
#pragma unroll
    for (int i = 0; i < 8; i++) {
        int wrow_g = pp0 - 59 + i * 32 + srow;           // >= 0 always
        wrow_g = wrow_g > (PPAD - 1) ? (PPAD - 1) : wrow_g;  // tile-24 tail clamp
        awin[i] = (b * PPAD + wrow_g) * C_IN + gxor8;
    }
#pragma unroll
    for (int i = 0; i < 4; i++) {
        int co = perm[b * C_OUT + i * 32 + srow];  // surviving channel gather
        wrowB[i] = co * C_IN + gxor8;
    }
    ushort_t* ldsA = Aw + t * 8;
    ushort_t* ldsB = Bs + t * 8;

    // B fragment LDS byte offsets (static, as before)
    int boff[2][4];
#pragma unroll
    for (int ks = 0; ks < 2; ks++) {
        int c = (lane >> 4) + ks * 4;
#pragma unroll
        for (int nt = 0; nt < 4; nt++) {
            int rb = waveN * 64 + nt * 16 + (lane & 15);
            boff[ks][nt] = (rb * 8 + (c ^ (rb & 7))) * 16;
        }
    }

    // A fragment window row base per mt (per-lane; taps add dy*58+dx)
    int wrb[4];
#pragma unroll
    for (int mt = 0; mt < 4; mt++) {
        int pl = p0 + waveM * 64 + mt * 16 + (lane & 15);
        pl = pl < HW ? pl : HW - 1;          // tail rows: read valid window, store masked
        int hh = pl / W_SZ, ww = pl - hh * W_SZ;
        wrb[mt] = (hh + 1) * WP + (ww + 1) - pp0 + 59;
    }

    f32x4 acc[4][4];
#pragma unroll
    for (int i = 0; i < 4; i++)
#pragma unroll
        for (int j = 0; j < 4; j++) acc[i][j] = (f32x4){0.f, 0.f, 0.f, 0.f};

    const char* Abc = (const char*)Aw;
    const char* Bbc = (const char*)Bs;

    for (int cq = 0; cq < 4; cq++) {
        const int ci0 = cq * 64;
        // stage the A pp-window ONCE per ci-quarter (8 x 4 KB)
#pragma unroll
        for (int i = 0; i < 8; i++)
            load_lds16(xbp + awin[i] + ci0, ldsA + i * 2048);
        for (int tap = 0; tap < 9; tap++) {
            const int dtap = (tap / 3 - 1) * WP + (tap % 3 - 1);
            const int woff = tap * (C_OUT * C_IN);
#pragma unroll
            for (int i = 0; i < 4; i++)
                load_lds16(Wt + wrowB[i] + woff + ci0, ldsB + i * 2048);
            __syncthreads();
#pragma unroll
            for (int ks = 0; ks < 2; ks++) {
                bf16x8 af[4], bf[4];
                const int c = (lane >> 4) + ks * 4;
#pragma unroll
                for (int mt = 0; mt < 4; mt++) {
                    int wr = wrb[mt] + dtap;
                    af[mt] = *(const bf16x8*)(Abc + wr * 128 + ((c ^ (wr & 7)) << 4));
                }
#pragma unroll
                for (int nt = 0; nt < 4; nt++) bf[nt] = *(const bf16x8*)(Bbc + boff[ks][nt]);
#pragma unroll
                for (int mt = 0; mt < 4; mt++)
#pragma unroll
                    for (int nt = 0; nt < 4; nt++)
                        acc[mt][nt] = __builtin_amdgcn_mfma_f32_16x16x32_bf16(
                            af[mt], bf[nt], acc[mt][nt], 0, 0, 0);
            }
            __syncthreads();
        }
    }

    // epilogue: y = relu(acc*inv + add) * cscale, scatter to real channel;
    // plus zero-fill the dead channels over the same p rows.
    int coK[4], coD[4];
    float invK[4], addK[4], tscK[4];
#pragma unroll
    for (int nt = 0; nt < 4; nt++) {
        int j = waveN * 64 + nt * 16 + (lane & 15);
        coK[nt] = perm[b * C_OUT + j];
        coD[nt] = perm[b * C_OUT + K_ZERO + j];
        invK[nt] = bninv[coK[nt]];
        addK[nt] = bnadd[coK[nt]];
        tscK[nt] = cscale[b * K_ZERO + j];
    }
    const float4 z4 = make_float4(0.f, 0.f, 0.f, 0.f);
#pragma unroll
    for (int mt = 0; mt < 4; mt++) {
        int pl0 = p0 + waveM * 64 + mt * 16 + (lane >> 4) * 4;
        if (pl0 < HW) {
#pragma unroll
            for (int nt = 0; nt < 4; nt++) {
                float inv = invK[nt], add = addK[nt], tsc = tscK[nt];
                float4 o;
                o.x = fmaxf(acc[mt][nt][0] * inv + add, 0.f) * tsc;
                o.y = fmaxf(acc[mt][nt][1] * inv + add, 0.f) * tsc;
                o.z = fmaxf(acc[mt][nt][2] * inv + add, 0.f) * tsc;
                o.w = fmaxf(acc[mt][nt][3] * inv + add, 0.f) * tsc;
                *(float4*)(out + (size_t)(b * C_OUT + coK[nt]) * HW + pl0) = o;
                *(float4*)(out + (size_t)(b * C_OUT + coD[nt]) * HW + pl0) = z4;
            }
        }
    }
}

// ---------------------------------------------------------------------------
extern "C" void kernel_launch(void* const* d_in, const int* in_sizes, int n_in,
                              void* d_out, int out_size, void* d_ws, size_t ws_size,
                              hipStream_t stream) {
    const float* x      = (const float*)d_in[0];
    const float* conv_w = (const float*)d_in[1];
    const float* gate_w = (const float*)d_in[2];
    const float* gate_b = (const float*)d_in[3];
    const float* bn_g   = (const float*)d_in[4];
    const float* bn_b   = (const float*)d_in[5];
    const float* bn_m   = (const float*)d_in[6];
    const float* bn_v   = (const float*)d_in[7];
    float* out = (float*)d_out;

    char* ws = (char*)d_ws;
    float*    s      = (float*)(ws + 0);          // 8192 f
    ushort_t* perm   = (ushort_t*)(ws + 32768);   // 32*256 u16 (16 KB)
    float*    cscale = (float*)(ws + 49152);      // 32*128 f  (16 KB)
    float*    bninv  = (float*)(ws + 65536);      // 256 f
    float*    bnadd  = (float*)(ws + 66560);      // 256 f
    ushort_t* Wt     = (ushort_t*)(ws + 67584);   // 589824 bf16
    ushort_t* xbp    = (ushort_t*)(ws + 1247232); // 32*58*58*256 bf16

    prep_w_kernel<<<2304, 256, 0, stream>>>(conv_w, bn_g, bn_b, bn_m, bn_v, Wt, bninv, bnadd, s);
    prep_x_kernel<<<dim3(4, 56, 32), 256, 0, stream>>>(x, xbp, s);
    gate_kernel<<<32, 256, 0, stream>>>(s, gate_w, gate_b, perm, cscale);
    conv_kernel<<<dim3(25 * 32), 256, 0, stream>>>(xbp, Wt, bninv, bnadd, perm, cscale, out);
}

// Round 6
// 320.402 us; speedup vs baseline: 1.0947x; 1.0791x over previous
//
#include <hip/hip_runtime.h>
#include <hip/hip_bf16.h>
#include <cstdint>

typedef unsigned short ushort_t;
typedef unsigned int uint_t;
typedef __bf16 bf16x8 __attribute__((ext_vector_type(8)));
typedef float f32x4 __attribute__((ext_vector_type(4)));

#define B_SZ 32
#define C_IN 256
#define C_OUT 256
#define H_SZ 56
#define W_SZ 56
#define HW 3136          // 56*56
#define HP 58            // padded H (halo 1 each side)
#define WP 58            // padded W
#define BN_EPS 1e-5f
#define K_ZERO 128       // channels zeroed per batch; 128 survive

__device__ __forceinline__ ushort_t f2bf(float f) {
    unsigned int u = __builtin_bit_cast(unsigned int, f);
    unsigned int r = (u + 0x7fffu + ((u >> 16) & 1u)) >> 16;
    return (ushort_t)r;
}

__device__ __forceinline__ void load_lds16(const void* gptr, void* ldsptr) {
    __builtin_amdgcn_global_load_lds(
        (const __attribute__((address_space(1))) unsigned int*)(uintptr_t)gptr,
        (__attribute__((address_space(3))) unsigned int*)(uintptr_t)ldsptr,
        16, 0, 0);
}

// ---------------------------------------------------------------------------
// Kernel 1 (COALESCED rework): one block per co. Old version read w at 36 B
// thread-stride (~9x line overfetch, 2304 blocks). Now: stage w[co][*][*]
// (9 KB) to LDS via float4 (coalesced), write Wt[tap][co][ci] with
// consecutive-ci ushort stores (512 B bursts). LDS read wl[ci*9+tap]:
// stride 9 mod 32 covers all banks <=2-way (free).
// ---------------------------------------------------------------------------
__global__ __launch_bounds__(256) void prep_w_kernel(const float* __restrict__ w,
                                                     const float* __restrict__ gamma,
                                                     const float* __restrict__ beta,
                                                     const float* __restrict__ mean,
                                                     const float* __restrict__ var,
                                                     ushort_t* __restrict__ Wt,
                                                     float* __restrict__ bninv,
                                                     float* __restrict__ bnadd,
                                                     float* __restrict__ s) {
    const int co = blockIdx.x, t = threadIdx.x;
    __shared__ float wl[2304];   // 9*256 floats = one co's 3x3x256 slice
    const float4* src4 = (const float4*)(w + (size_t)co * 2304);
    for (int i = t; i < 576; i += 256) ((float4*)wl)[i] = src4[i];
    if (co < 32) s[co * 256 + t] = 0.f;
    if (co == 32) {
        float inv = gamma[t] * rsqrtf(var[t] + BN_EPS);
        bninv[t] = inv;
        bnadd[t] = beta[t] - mean[t] * inv;
    }
    __syncthreads();
    for (int i = t; i < 2304; i += 256) {
        int tap = i >> 8, ci = i & 255;
        Wt[tap * (C_OUT * C_IN) + co * C_IN + ci] = f2bf(wl[ci * 9 + tap]);
    }
}

// ---------------------------------------------------------------------------
// Kernel 2: x NCHW fp32 -> padded NHWC bf16, fused abs-mean partials + halo.
// grid: (4 ci-tiles, 56 h, 32 b), block 256. Main store widened to uint4.
// ---------------------------------------------------------------------------
__global__ __launch_bounds__(256) void prep_x_kernel(const float* __restrict__ x,
                                                     ushort_t* __restrict__ xbp,
                                                     float* __restrict__ s) {
    const int cit = blockIdx.x, h = blockIdx.y, b = blockIdx.z;
    __shared__ float tile[64][57];
    __shared__ float red2[256];
    const int t = threadIdx.x;
    const float* src = x + ((size_t)(b * C_IN + cit * 64) * H_SZ + h) * W_SZ;
    for (int i = t; i < 64 * 14; i += 256) {
        int ci = i / 14, w4 = (i - ci * 14) * 4;
        float4 v = *(const float4*)(src + (size_t)ci * HW + w4);
        tile[ci][w4] = v.x; tile[ci][w4 + 1] = v.y;
        tile[ci][w4 + 2] = v.z; tile[ci][w4 + 3] = v.w;
    }
    __syncthreads();
    {
        int ci = t & 63, wg = t >> 6;
        float a = 0.f;
#pragma unroll
        for (int j = 0; j < 14; j++) a += fabsf(tile[ci][wg * 14 + j]);
        red2[t] = a;
    }
    __syncthreads();
    if (t < 64) {
        float tot = red2[t] + red2[t + 64] + red2[t + 128] + red2[t + 192];
        atomicAdd(&s[b * C_IN + cit * 64 + t], tot * (1.0f / (float)HW));
    }
    const uint2 z2 = make_uint2(0u, 0u);
    for (int i = t; i < W_SZ * 8; i += 256) {
        int w = i >> 3, c8 = (i & 7) * 8;
        uint4 v;
        v.x = (uint_t)f2bf(tile[c8][w])     | ((uint_t)f2bf(tile[c8 + 1][w]) << 16);
        v.y = (uint_t)f2bf(tile[c8 + 2][w]) | ((uint_t)f2bf(tile[c8 + 3][w]) << 16);
        v.z = (uint_t)f2bf(tile[c8 + 4][w]) | ((uint_t)f2bf(tile[c8 + 5][w]) << 16);
        v.w = (uint_t)f2bf(tile[c8 + 6][w]) | ((uint_t)f2bf(tile[c8 + 7][w]) << 16);
        size_t dst = ((size_t)((b * HP + h + 1) * WP + (w + 1))) * C_IN + cit * 64 + c8;
        *(uint4*)&xbp[dst] = v;
    }
    if (t < 32) {
        int side = t >> 4, c4 = (t & 15) * 4;
        size_t dst = ((size_t)((b * HP + h + 1) * WP + side * 57)) * C_IN + cit * 64 + c4;
        *(uint2*)&xbp[dst] = z2;
    }
    if (h == 0 || h == 55) {
        int prow = (h == 0) ? 0 : 57;
        for (int i = t; i < 58 * 16; i += 256) {
            int w = i >> 4, c4 = (i & 15) * 4;
            size_t dst = ((size_t)((b * HP + prow) * WP + w)) * C_IN + cit * 64 + c4;
            *(uint2*)&xbp[dst] = z2;
        }
    }
}

// ---------------------------------------------------------------------------
// Kernel 3: gate -> per-batch channel permutation + compacted scales.
// Dot loop float4-vectorized; rank/renorm logic unchanged.
// ---------------------------------------------------------------------------
__global__ __launch_bounds__(256) void gate_kernel(const float* __restrict__ s,
                                                   const float* __restrict__ gw,
                                                   const float* __restrict__ gb,
                                                   ushort_t* __restrict__ perm,
                                                   float* __restrict__ cscale) {
    const int b = blockIdx.x, t = threadIdx.x;
    __shared__ float sh_s[C_IN], sh_g[C_OUT], red[256];
    sh_s[t] = s[b * C_IN + t];
    __syncthreads();
    float acc = gb[t];
    const float4* s4 = (const float4*)sh_s;
    const float4* w4 = (const float4*)(gw + (size_t)t * C_IN);
    for (int ci = 0; ci < C_IN / 4; ci++) {
        float4 a = s4[ci], wv = w4[ci];
        acc += a.x * wv.x + a.y * wv.y + a.z * wv.z + a.w * wv.w;
    }
    float g = fmaxf(acc, 0.f);
    sh_g[t] = g;
    __syncthreads();
    int cnt = 0;
    for (int j = 0; j < C_OUT; j++) {
        float gj = sh_g[j];
        cnt += (gj < g) || (gj == g && j < t);
    }
    float tv = (cnt >= K_ZERO) ? g : 0.f;
    red[t] = tv;
    __syncthreads();
    for (int off = 128; off > 0; off >>= 1) {
        if (t < off) red[t] += red[t + off];
        __syncthreads();
    }
    if (cnt >= K_ZERO) {
        int pos = cnt - K_ZERO;
        perm[b * C_OUT + pos] = (ushort_t)t;
        cscale[b * K_ZERO + pos] = tv * ((float)C_OUT / red[0]);
    } else {
        perm[b * C_OUT + K_ZERO + cnt] = (ushort_t)t;
    }
}

// ---------------------------------------------------------------------------
// Kernel 4: implicit-GEMM conv + BN + ReLU over SURVIVING channels only.
// EXACT r2 version (verified 100 us, FETCH 35 MB, MfmaUtil 25%):
//  - cq OUTER / tap INNER: per-XCD working set partitioned by 4 (the real
//    L2 fix; ~1.7 MB A-slice per epoch fits 4 MB L2).
//  - per-tap A staging with static LDS fragment offsets (A-window variant
//    regressed twice: r3/r4 both 134 us -> concluded + reverted).
//  - chunked XCD swizzle (800%8==0 bijective).
// ---------------------------------------------------------------------------
__global__ __launch_bounds__(256, 3) void conv_kernel(const ushort_t* __restrict__ xbp,
                                                      const ushort_t* __restrict__ Wt,
                                                      const float* __restrict__ bninv,
                                                      const float* __restrict__ bnadd,
                                                      const ushort_t* __restrict__ perm,
                                                      const float* __restrict__ cscale,
                                                      float* __restrict__ out) {
    __shared__ __align__(16) ushort_t As[128 * 64];  // 16 KB
    __shared__ __align__(16) ushort_t Bs[128 * 64];  // 16 KB
    const int t = threadIdx.x;
    const int bxr = blockIdx.x;
    const int L = (bxr & 7) * 100 + (bxr >> 3);
    const int b = L / 25;          // 0..31, 4 consecutive batches per XCD
    const int tile = L - b * 25;   // 0..24 p-tiles within batch
    const int lane = t & 63;
    const int wv = t >> 6;
    const int waveM = wv >> 1, waveN = wv & 1;

    // staging: chunk q = i*256+t -> row i*32+(t>>3), stored col t&7,
    // global col (t&7)^(row&7)
    const int srow = t >> 3;
    const int gxor8 = ((t & 7) ^ (srow & 7)) * 8;
    int arow[4], wrow[4];
#pragma unroll
    for (int i = 0; i < 4; i++) {
        int pl = tile * 128 + i * 32 + srow;
        pl = pl < HW ? pl : HW - 1;          // clamp tail tile inside batch
        int hh = pl / W_SZ, ww = pl - hh * W_SZ;
        arow[i] = ((b * HP + hh + 1) * WP + (ww + 1)) * C_IN + gxor8;
        int co = perm[b * C_OUT + i * 32 + srow];  // surviving channel gather
        wrow[i] = co * C_IN + gxor8;
    }
    ushort_t* ldsA = As + t * 8;
    ushort_t* ldsB = Bs + t * 8;

    // fragment LDS byte offsets: row r, global chunk c stored at c^(r&7)
    int aoff[2][4], boff[2][4];
#pragma unroll
    for (int ks = 0; ks < 2; ks++) {
        int c = (lane >> 4) + ks * 4;
#pragma unroll
        for (int mt = 0; mt < 4; mt++) {
            int ra = waveM * 64 + mt * 16 + (lane & 15);
            aoff[ks][mt] = (ra * 8 + (c ^ (ra & 7))) * 16;
            int rb = waveN * 64 + mt * 16 + (lane & 15);
            boff[ks][mt] = (rb * 8 + (c ^ (rb & 7))) * 16;
        }
    }

    f32x4 acc[4][4];
#pragma unroll
    for (int i = 0; i < 4; i++)
#pragma unroll
        for (int j = 0; j < 4; j++) acc[i][j] = (f32x4){0.f, 0.f, 0.f, 0.f};

    const char* Ab = (const char*)As;
    const char* Bb = (const char*)Bs;

    for (int cq = 0; cq < 4; cq++) {
        const int ci0 = cq * 64;
        for (int tap = 0; tap < 9; tap++) {
            const int doff = ((tap / 3 - 1) * WP + (tap % 3 - 1)) * C_IN;
            const int woff = tap * (C_OUT * C_IN);
#pragma unroll
            for (int i = 0; i < 4; i++) {
                load_lds16(xbp + arow[i] + doff + ci0, ldsA + i * 2048);
                load_lds16(Wt + wrow[i] + woff + ci0, ldsB + i * 2048);
            }
            __syncthreads();
#pragma unroll
            for (int ks = 0; ks < 2; ks++) {
                bf16x8 af[4], bf[4];
#pragma unroll
                for (int mt = 0; mt < 4; mt++) af[mt] = *(const bf16x8*)(Ab + aoff[ks][mt]);
#pragma unroll
                for (int nt = 0; nt < 4; nt++) bf[nt] = *(const bf16x8*)(Bb + boff[ks][nt]);
#pragma unroll
                for (int mt = 0; mt < 4; mt++)
#pragma unroll
                    for (int nt = 0; nt < 4; nt++)
                        acc[mt][nt] = __builtin_amdgcn_mfma_f32_16x16x32_bf16(
                            af[mt], bf[nt], acc[mt][nt], 0, 0, 0);
            }
            __syncthreads();
        }
    }

    // epilogue: y = relu(acc*inv + add) * cscale, scatter to real channel;
    // plus zero-fill the dead channels over the same p rows.
    int coK[4], coD[4];
    float invK[4], addK[4], tscK[4];
#pragma unroll
    for (int nt = 0; nt < 4; nt++) {
        int j = waveN * 64 + nt * 16 + (lane & 15);
        coK[nt] = perm[b * C_OUT + j];
        coD[nt] = perm[b * C_OUT + K_ZERO + j];
        invK[nt] = bninv[coK[nt]];
        addK[nt] = bnadd[coK[nt]];
        tscK[nt] = cscale[b * K_ZERO + j];
    }
    const float4 z4 = make_float4(0.f, 0.f, 0.f, 0.f);
#pragma unroll
    for (int mt = 0; mt < 4; mt++) {
        int pl0 = tile * 128 + waveM * 64 + mt * 16 + (lane >> 4) * 4;
        if (pl0 < HW) {
#pragma unroll
            for (int nt = 0; nt < 4; nt++) {
                float inv = invK[nt], add = addK[nt], tsc = tscK[nt];
                float4 o;
                o.x = fmaxf(acc[mt][nt][0] * inv + add, 0.f) * tsc;
                o.y = fmaxf(acc[mt][nt][1] * inv + add, 0.f) * tsc;
                o.z = fmaxf(acc[mt][nt][2] * inv + add, 0.f) * tsc;
                o.w = fmaxf(acc[mt][nt][3] * inv + add, 0.f) * tsc;
                *(float4*)(out + (size_t)(b * C_OUT + coK[nt]) * HW + pl0) = o;
                *(float4*)(out + (size_t)(b * C_OUT + coD[nt]) * HW + pl0) = z4;
            }
        }
    }
}

// ---------------------------------------------------------------------------
extern "C" void kernel_launch(void* const* d_in, const int* in_sizes, int n_in,
                              void* d_out, int out_size, void* d_ws, size_t ws_size,
                              hipStream_t stream) {
    const float* x      = (const float*)d_in[0];
    const float* conv_w = (const float*)d_in[1];
    const float* gate_w = (const float*)d_in[2];
    const float* gate_b = (const float*)d_in[3];
    const float* bn_g   = (const float*)d_in[4];
    const float* bn_b   = (const float*)d_in[5];
    const float* bn_m   = (const float*)d_in[6];
    const float* bn_v   = (const float*)d_in[7];
    float* out = (float*)d_out;

    char* ws = (char*)d_ws;
    float*    s      = (float*)(ws + 0);          // 8192 f
    ushort_t* perm   = (ushort_t*)(ws + 32768);   // 32*256 u16 (16 KB)
    float*    cscale = (float*)(ws + 49152);      // 32*128 f  (16 KB)
    float*    bninv  = (float*)(ws + 65536);      // 256 f
    float*    bnadd  = (float*)(ws + 66560);      // 256 f
    ushort_t* Wt     = (ushort_t*)(ws + 67584);   // 589824 bf16
    ushort_t* xbp    = (ushort_t*)(ws + 1247232); // 32*58*58*256 bf16

    prep_w_kernel<<<256, 256, 0, stream>>>(conv_w, bn_g, bn_b, bn_m, bn_v, Wt, bninv, bnadd, s);
    prep_x_kernel<<<dim3(4, 56, 32), 256, 0, stream>>>(x, xbp, s);
    gate_kernel<<<32, 256, 0, stream>>>(s, gate_w, gate_b, perm, cscale);
    conv_kernel<<<dim3(25 * 32), 256, 0, stream>>>(xbp, Wt, bninv, bnadd, perm, cscale, out);
}

// Round 7
// 319.362 us; speedup vs baseline: 1.0982x; 1.0033x over previous
//
#include <hip/hip_runtime.h>
#include <hip/hip_bf16.h>
#include <cstdint>

typedef unsigned short ushort_t;
typedef unsigned int uint_t;
typedef __bf16 bf16x8 __attribute__((ext_vector_type(8)));
typedef float f32x4 __attribute__((ext_vector_type(4)));

#define B_SZ 32
#define C_IN 256
#define C_OUT 256
#define H_SZ 56
#define W_SZ 56
#define HW 3136          // 56*56
#define HP 58            // padded H (halo 1 each side)
#define WP 58            // padded W
#define BN_EPS 1e-5f
#define K_ZERO 128       // channels zeroed per batch; 128 survive
#define NPX 7168         // prep_x role blocks: 4 cit * 56 h * 32 b

__device__ __forceinline__ ushort_t f2bf(float f) {
    unsigned int u = __builtin_bit_cast(unsigned int, f);
    unsigned int r = (u + 0x7fffu + ((u >> 16) & 1u)) >> 16;
    return (ushort_t)r;
}

__device__ __forceinline__ void load_lds16(const void* gptr, void* ldsptr) {
    __builtin_amdgcn_global_load_lds(
        (const __attribute__((address_space(1))) unsigned int*)(uintptr_t)gptr,
        (__attribute__((address_space(3))) unsigned int*)(uintptr_t)ldsptr,
        16, 0, 0);
}

// ---------------------------------------------------------------------------
// Kernel 1 (MERGED prep): blocks [0,7168) do prep_x (x NCHW fp32 -> padded
// NHWC bf16 + per-(b,h) abs-mean partials, NO atomics: s_part[b][h][ci] is
// written exactly once -> no zeroing pass, no cross-kernel ordering dep).
// Blocks [7168,7424) do prep_w (coalesced LDS-staged transpose of conv_w
// to Wt[tap][co][ci] bf16 + BN consts). One launch, one boundary saved.
// ---------------------------------------------------------------------------
__global__ __launch_bounds__(256) void prep_kernel(const float* __restrict__ x,
                                                   const float* __restrict__ w,
                                                   const float* __restrict__ gamma,
                                                   const float* __restrict__ beta,
                                                   const float* __restrict__ mean,
                                                   const float* __restrict__ var,
                                                   ushort_t* __restrict__ Wt,
                                                   float* __restrict__ bninv,
                                                   float* __restrict__ bnadd,
                                                   float* __restrict__ s_part,
                                                   ushort_t* __restrict__ xbp) {
    const int bx = blockIdx.x, t = threadIdx.x;
    __shared__ __align__(16) char smem[15616];   // max(tile 14592+red2 1024, wl 9216)

    if (bx >= NPX) {
        // ---- prep_w role: one block per co ----
        const int co = bx - NPX;
        float* wl = (float*)smem;   // 2304 floats
        const float4* src4 = (const float4*)(w + (size_t)co * 2304);
        for (int i = t; i < 576; i += 256) ((float4*)wl)[i] = src4[i];
        if (co == 32) {
            float inv = gamma[t] * rsqrtf(var[t] + BN_EPS);
            bninv[t] = inv;
            bnadd[t] = beta[t] - mean[t] * inv;
        }
        __syncthreads();
        for (int i = t; i < 2304; i += 256) {
            int tap = i >> 8, ci = i & 255;
            Wt[tap * (C_OUT * C_IN) + co * C_IN + ci] = f2bf(wl[ci * 9 + tap]);
        }
        return;
    }

    // ---- prep_x role: bx = (b*56+h)*4 + cit ----
    const int cit = bx & 3;
    const int hb = bx >> 2;        // b*56 + h
    const int h = hb % 56;
    const int b = hb / 56;
    float (*tile)[57] = (float (*)[57])smem;         // 64 x 57 fp32
    float* red2 = (float*)(smem + 14592);            // 256 fp32
    const float* src = x + ((size_t)(b * C_IN + cit * 64) * H_SZ + h) * W_SZ;
    for (int i = t; i < 64 * 14; i += 256) {
        int ci = i / 14, w4 = (i - ci * 14) * 4;
        float4 v = *(const float4*)(src + (size_t)ci * HW + w4);
        tile[ci][w4] = v.x; tile[ci][w4 + 1] = v.y;
        tile[ci][w4 + 2] = v.z; tile[ci][w4 + 3] = v.w;
    }
    __syncthreads();
    {
        int ci = t & 63, wg = t >> 6;
        float a = 0.f;
#pragma unroll
        for (int j = 0; j < 14; j++) a += fabsf(tile[ci][wg * 14 + j]);
        red2[t] = a;
    }
    __syncthreads();
    if (t < 64) {
        float tot = red2[t] + red2[t + 64] + red2[t + 128] + red2[t + 192];
        s_part[(size_t)hb * C_IN + cit * 64 + t] = tot * (1.0f / (float)HW);
    }
    const uint2 z2 = make_uint2(0u, 0u);
    for (int i = t; i < W_SZ * 8; i += 256) {
        int w_ = i >> 3, c8 = (i & 7) * 8;
        uint4 v;
        v.x = (uint_t)f2bf(tile[c8][w_])     | ((uint_t)f2bf(tile[c8 + 1][w_]) << 16);
        v.y = (uint_t)f2bf(tile[c8 + 2][w_]) | ((uint_t)f2bf(tile[c8 + 3][w_]) << 16);
        v.z = (uint_t)f2bf(tile[c8 + 4][w_]) | ((uint_t)f2bf(tile[c8 + 5][w_]) << 16);
        v.w = (uint_t)f2bf(tile[c8 + 6][w_]) | ((uint_t)f2bf(tile[c8 + 7][w_]) << 16);
        size_t dst = ((size_t)((b * HP + h + 1) * WP + (w_ + 1))) * C_IN + cit * 64 + c8;
        *(uint4*)&xbp[dst] = v;
    }
    if (t < 32) {
        int side = t >> 4, c4 = (t & 15) * 4;
        size_t dst = ((size_t)((b * HP + h + 1) * WP + side * 57)) * C_IN + cit * 64 + c4;
        *(uint2*)&xbp[dst] = z2;
    }
    if (h == 0 || h == 55) {
        int prow = (h == 0) ? 0 : 57;
        for (int i = t; i < 58 * 16; i += 256) {
            int w_ = i >> 4, c4 = (i & 15) * 4;
            size_t dst = ((size_t)((b * HP + prow) * WP + w_)) * C_IN + cit * 64 + c4;
            *(uint2*)&xbp[dst] = z2;
        }
    }
}

// ---------------------------------------------------------------------------
// Kernel 2: gate -> per-batch channel permutation + compacted scales.
// Now reduces the 56 per-h s_part partials itself (coalesced 256 B bursts
// per wave, L2-resident) -- replaces the old atomic-accumulated s.
// ---------------------------------------------------------------------------
__global__ __launch_bounds__(256) void gate_kernel(const float* __restrict__ s_part,
                                                   const float* __restrict__ gw,
                                                   const float* __restrict__ gb,
                                                   ushort_t* __restrict__ perm,
                                                   float* __restrict__ cscale) {
    const int b = blockIdx.x, t = threadIdx.x;
    __shared__ float sh_s[C_IN], sh_g[C_OUT], red[256];
    {
        const float* sp = s_part + (size_t)b * 56 * C_IN + t;
        float v = 0.f;
#pragma unroll 8
        for (int h = 0; h < 56; h++) v += sp[(size_t)h * C_IN];
        sh_s[t] = v;
    }
    __syncthreads();
    float acc = gb[t];
    const float4* s4 = (const float4*)sh_s;
    const float4* w4 = (const float4*)(gw + (size_t)t * C_IN);
    for (int ci = 0; ci < C_IN / 4; ci++) {
        float4 a = s4[ci], wv = w4[ci];
        acc += a.x * wv.x + a.y * wv.y + a.z * wv.z + a.w * wv.w;
    }
    float g = fmaxf(acc, 0.f);
    sh_g[t] = g;
    __syncthreads();
    int cnt = 0;
    for (int j = 0; j < C_OUT; j++) {
        float gj = sh_g[j];
        cnt += (gj < g) || (gj == g && j < t);
    }
    float tv = (cnt >= K_ZERO) ? g : 0.f;
    red[t] = tv;
    __syncthreads();
    for (int off = 128; off > 0; off >>= 1) {
        if (t < off) red[t] += red[t + off];
        __syncthreads();
    }
    if (cnt >= K_ZERO) {
        int pos = cnt - K_ZERO;
        perm[b * C_OUT + pos] = (ushort_t)t;
        cscale[b * K_ZERO + pos] = tv * ((float)C_OUT / red[0]);
    } else {
        perm[b * C_OUT + K_ZERO + cnt] = (ushort_t)t;
    }
}

// ---------------------------------------------------------------------------
// Kernel 3: implicit-GEMM conv + BN + ReLU over SURVIVING channels only.
// VERBATIM r2/r6-verified version (100 us, FETCH 35 MB, MfmaUtil 25%):
//  - cq OUTER / tap INNER (L2 working-set partition by 4)
//  - per-tap A staging, static LDS fragment offsets, row-keyed XOR swizzle
//  - chunked XCD swizzle (800%8==0 bijective)
// ---------------------------------------------------------------------------
__global__ __launch_bounds__(256, 3) void conv_kernel(const ushort_t* __restrict__ xbp,
                                                      const ushort_t* __restrict__ Wt,
                                                      const float* __restrict__ bninv,
                                                      const float* __restrict__ bnadd,
                                                      const ushort_t* __restrict__ perm,
                                                      const float* __restrict__ cscale,
                                                      float* __restrict__ out) {
    __shared__ __align__(16) ushort_t As[128 * 64];  // 16 KB
    __shared__ __align__(16) ushort_t Bs[128 * 64];  // 16 KB
    const int t = threadIdx.x;
    const int bxr = blockIdx.x;
    const int L = (bxr & 7) * 100 + (bxr >> 3);
    const int b = L / 25;          // 0..31, 4 consecutive batches per XCD
    const int tile = L - b * 25;   // 0..24 p-tiles within batch
    const int lane = t & 63;
    const int wv = t >> 6;
    const int waveM = wv >> 1, waveN = wv & 1;

    const int srow = t >> 3;
    const int gxor8 = ((t & 7) ^ (srow & 7)) * 8;
    int arow[4], wrow[4];
#pragma unroll
    for (int i = 0; i < 4; i++) {
        int pl = tile * 128 + i * 32 + srow;
        pl = pl < HW ? pl : HW - 1;          // clamp tail tile inside batch
        int hh = pl / W_SZ, ww = pl - hh * W_SZ;
        arow[i] = ((b * HP + hh + 1) * WP + (ww + 1)) * C_IN + gxor8;
        int co = perm[b * C_OUT + i * 32 + srow];  // surviving channel gather
        wrow[i] = co * C_IN + gxor8;
    }
    ushort_t* ldsA = As + t * 8;
    ushort_t* ldsB = Bs + t * 8;

    int aoff[2][4], boff[2][4];
#pragma unroll
    for (int ks = 0; ks < 2; ks++) {
        int c = (lane >> 4) + ks * 4;
#pragma unroll
        for (int mt = 0; mt < 4; mt++) {
            int ra = waveM * 64 + mt * 16 + (lane & 15);
            aoff[ks][mt] = (ra * 8 + (c ^ (ra & 7))) * 16;
            int rb = waveN * 64 + mt * 16 + (lane & 15);
            boff[ks][mt] = (rb * 8 + (c ^ (rb & 7))) * 16;
        }
    }

    f32x4 acc[4][4];
#pragma unroll
    for (int i = 0; i < 4; i++)
#pragma unroll
        for (int j = 0; j < 4; j++) acc[i][j] = (f32x4){0.f, 0.f, 0.f, 0.f};

    const char* Ab = (const char*)As;
    const char* Bb = (const char*)Bs;

    for (int cq = 0; cq < 4; cq++) {
        const int ci0 = cq * 64;
        for (int tap = 0; tap < 9; tap++) {
            const int doff = ((tap / 3 - 1) * WP + (tap % 3 - 1)) * C_IN;
            const int woff = tap * (C_OUT * C_IN);
#pragma unroll
            for (int i = 0; i < 4; i++) {
                load_lds16(xbp + arow[i] + doff + ci0, ldsA + i * 2048);
                load_lds16(Wt + wrow[i] + woff + ci0, ldsB + i * 2048);
            }
            __syncthreads();
#pragma unroll
            for (int ks = 0; ks < 2; ks++) {
                bf16x8 af[4], bf[4];
#pragma unroll
                for (int mt = 0; mt < 4; mt++) af[mt] = *(const bf16x8*)(Ab + aoff[ks][mt]);
#pragma unroll
                for (int nt = 0; nt < 4; nt++) bf[nt] = *(const bf16x8*)(Bb + boff[ks][nt]);
#pragma unroll
                for (int mt = 0; mt < 4; mt++)
#pragma unroll
                    for (int nt = 0; nt < 4; nt++)
                        acc[mt][nt] = __builtin_amdgcn_mfma_f32_16x16x32_bf16(
                            af[mt], bf[nt], acc[mt][nt], 0, 0, 0);
            }
            __syncthreads();
        }
    }

    int coK[4], coD[4];
    float invK[4], addK[4], tscK[4];
#pragma unroll
    for (int nt = 0; nt < 4; nt++) {
        int j = waveN * 64 + nt * 16 + (lane & 15);
        coK[nt] = perm[b * C_OUT + j];
        coD[nt] = perm[b * C_OUT + K_ZERO + j];
        invK[nt] = bninv[coK[nt]];
        addK[nt] = bnadd[coK[nt]];
        tscK[nt] = cscale[b * K_ZERO + j];
    }
    const float4 z4 = make_float4(0.f, 0.f, 0.f, 0.f);
#pragma unroll
    for (int mt = 0; mt < 4; mt++) {
        int pl0 = tile * 128 + waveM * 64 + mt * 16 + (lane >> 4) * 4;
        if (pl0 < HW) {
#pragma unroll
            for (int nt = 0; nt < 4; nt++) {
                float inv = invK[nt], add = addK[nt], tsc = tscK[nt];
                float4 o;
                o.x = fmaxf(acc[mt][nt][0] * inv + add, 0.f) * tsc;
                o.y = fmaxf(acc[mt][nt][1] * inv + add, 0.f) * tsc;
                o.z = fmaxf(acc[mt][nt][2] * inv + add, 0.f) * tsc;
                o.w = fmaxf(acc[mt][nt][3] * inv + add, 0.f) * tsc;
                *(float4*)(out + (size_t)(b * C_OUT + coK[nt]) * HW + pl0) = o;
                *(float4*)(out + (size_t)(b * C_OUT + coD[nt]) * HW + pl0) = z4;
            }
        }
    }
}

// ---------------------------------------------------------------------------
extern "C" void kernel_launch(void* const* d_in, const int* in_sizes, int n_in,
                              void* d_out, int out_size, void* d_ws, size_t ws_size,
                              hipStream_t stream) {
    const float* x      = (const float*)d_in[0];
    const float* conv_w = (const float*)d_in[1];
    const float* gate_w = (const float*)d_in[2];
    const float* gate_b = (const float*)d_in[3];
    const float* bn_g   = (const float*)d_in[4];
    const float* bn_b   = (const float*)d_in[5];
    const float* bn_m   = (const float*)d_in[6];
    const float* bn_v   = (const float*)d_in[7];
    float* out = (float*)d_out;

    char* ws = (char*)d_ws;
    float*    s_part = (float*)(ws + 0);          // 32*56*256 f32 = 1835008 B
    ushort_t* perm   = (ushort_t*)(ws + 1835008); // 32*256 u16 (16 KB)
    float*    cscale = (float*)(ws + 1851392);    // 32*128 f  (16 KB)
    float*    bninv  = (float*)(ws + 1867776);    // 256 f
    float*    bnadd  = (float*)(ws + 1868800);    // 256 f
    ushort_t* Wt     = (ushort_t*)(ws + 1869824); // 589824 bf16 (1179648 B)
    ushort_t* xbp    = (ushort_t*)(ws + 3049472); // 32*58*58*256 bf16

    prep_kernel<<<NPX + 256, 256, 0, stream>>>(x, conv_w, bn_g, bn_b, bn_m, bn_v,
                                               Wt, bninv, bnadd, s_part, xbp);
    gate_kernel<<<32, 256, 0, stream>>>(s_part, gate_w, gate_b, perm, cscale);
    conv_kernel<<<dim3(25 * 32), 256, 0, stream>>>(xbp, Wt, bninv, bnadd, perm, cscale, out);
}